// Round 6
// baseline (626.414 us; speedup 1.0000x reference)
//
#include <hip/hip_runtime.h>
#include <stdint.h>

#define DIM 128
#define LPAD 136   // padded LDS row stride (bf16): b128 read pattern ~conflict-free

static constexpr long long NTOT = 299593LL;

using bf16x8 = __attribute__((ext_vector_type(8))) __bf16;
using f32x4  = __attribute__((ext_vector_type(4))) float;

__device__ __forceinline__ float relu(float x){ return x > 0.f ? x : 0.f; }
__device__ __forceinline__ __bf16 tobf(float x){ return (__bf16)x; }

__device__ __forceinline__ void mfma_acc(f32x4& acc, bf16x8 a, bf16x8 b){
    acc = __builtin_amdgcn_mfma_f32_16x16x32_bf16(a, b, acc, 0, 0, 0);
}

// cooperative: 128x128 bf16 weight (row stride src_stride) -> padded LDS
__device__ __forceinline__ void load_w_lds(const __bf16* __restrict__ wsrc,
                                           __bf16* lds, int src_stride){
    int t = threadIdx.x;
    #pragma unroll
    for (int i = 0; i < 8; ++i){
        int idx = t + i*256;
        int row = idx >> 4, col8 = (idx & 15) << 3;
        *(uint4*)(&lds[row*LPAD + col8]) = *(const uint4*)(wsrc + row*src_stride + col8);
    }
}

// ---- prep: weights fp32->bf16 ----
__global__ __launch_bounds__(256) void prep_kernel(
    const float* __restrict__ Ws, const float* __restrict__ Wc,
    const float* __restrict__ Wx, const float* __restrict__ Wf,
    __bf16* __restrict__ wts)
{
    int idx = blockIdx.x*256 + threadIdx.x;
    if      (idx < 16384) wts[idx] = tobf(Ws[idx]);
    else if (idx < 32768) wts[idx] = tobf(Wc[idx - 16384]);
    else if (idx < 49152) wts[idx] = tobf(Wx[idx - 32768]);
    else if (idx < 81920) wts[idx] = tobf(Wf[idx - 49152]);
}

// ============================================================================
// up stage 1 (streaming, barrier-free loop): sib[g] = mean_s relu(Ws.child + bs)
// LEAF: children come from fp32 init (and bf16 leaf agg is materialized).
// n_child must be a multiple of 128 (true for levels 5,4,3).
// ============================================================================
template<bool LEAF>
__global__ __launch_bounds__(256, 4) void up_sib_kernel(
    const __bf16* __restrict__ wts,     // Ws @0
    const float* __restrict__ init,
    const float* __restrict__ bs,
    __bf16* __restrict__ agg,
    __bf16* __restrict__ sib,
    long long child_base, long long n_child)
{
    __shared__ __bf16 lds_w[128*LPAD];
    const int t = threadIdx.x;
    const int w = t >> 6, lane = t & 63, quad = lane >> 4, l15 = lane & 15;
    const int ntiles = (int)(n_child >> 7);
    const int G = gridDim.x;

    load_w_lds(wts, lds_w, 128);
    __syncthreads();

    for (int tile = blockIdx.x; tile < ntiles; tile += G){
        bf16x8 af[2][4];
        #pragma unroll
        for (int tt = 0; tt < 2; ++tt){
            const long long r = (long long)tile*128 + w*32 + tt*16 + l15;
            const long long base = (child_base + r)*DIM;
            if (LEAF){
                #pragma unroll
                for (int ks = 0; ks < 4; ++ks){
                    const float* p = init + base + ks*32 + quad*8;
                    float4 v0 = *(const float4*)p;
                    float4 v1 = *(const float4*)(p + 4);
                    bf16x8 a;
                    a[0]=tobf(v0.x); a[1]=tobf(v0.y); a[2]=tobf(v0.z); a[3]=tobf(v0.w);
                    a[4]=tobf(v1.x); a[5]=tobf(v1.y); a[6]=tobf(v1.z); a[7]=tobf(v1.w);
                    af[tt][ks] = a;
                    *(uint4*)(agg + base + ks*32 + quad*8) = *(uint4*)&a;  // leaf agg
                }
            } else {
                #pragma unroll
                for (int ks = 0; ks < 4; ++ks)
                    af[tt][ks] = *(const bf16x8*)(agg + base + ks*32 + quad*8);
            }
        }
        f32x4 acc[2][8];
        #pragma unroll
        for (int tt = 0; tt < 2; ++tt)
            #pragma unroll
            for (int i = 0; i < 8; ++i) acc[tt][i] = f32x4{0.f,0.f,0.f,0.f};
        #pragma unroll
        for (int ks = 0; ks < 4; ++ks){
            #pragma unroll
            for (int nt = 0; nt < 8; ++nt){
                bf16x8 bfrag = *(const bf16x8*)&lds_w[(nt*16 + l15)*LPAD + ks*32 + quad*8];
                mfma_acc(acc[0][nt], af[0][ks], bfrag);
                mfma_acc(acc[1][nt], af[1][ks], bfrag);
            }
        }
        // lane's 4 acc rows = one sibling group -> one sib row
        #pragma unroll
        for (int tt = 0; tt < 2; ++tt){
            const long long g = (long long)tile*32 + w*8 + tt*4 + quad;
            #pragma unroll
            for (int nt = 0; nt < 8; ++nt){
                int col = nt*16 + l15;
                float b = bs[col];
                float s = relu(acc[tt][nt][0]+b) + relu(acc[tt][nt][1]+b)
                        + relu(acc[tt][nt][2]+b) + relu(acc[tt][nt][3]+b);
                sib[g*DIM + col] = tobf(s * 0.25f);
            }
        }
    }
}

// ============================================================================
// up stage 2 (streaming, barrier-free loop):
// agg[parent] = init[parent] + 0.5 * sum_t relu(Wc.sib[parent*2+t] + bc)
// n_sib must be a multiple of 128 (true for levels 5,4,3).
// ============================================================================
__global__ __launch_bounds__(256, 4) void up_par_kernel(
    const __bf16* __restrict__ wts,     // Wc @16384
    const float* __restrict__ init,
    const float* __restrict__ bc,
    const __bf16* __restrict__ sib,
    __bf16* __restrict__ agg,
    long long parent_base, long long n_sib)
{
    __shared__ __bf16 lds_w[128*LPAD];
    const int t = threadIdx.x;
    const int w = t >> 6, lane = t & 63, quad = lane >> 4, l15 = lane & 15;
    const int ntiles = (int)(n_sib >> 7);
    const int G = gridDim.x;

    load_w_lds(wts + 16384, lds_w, 128);
    __syncthreads();

    for (int tile = blockIdx.x; tile < ntiles; tile += G){
        bf16x8 af[2][4];
        #pragma unroll
        for (int tt = 0; tt < 2; ++tt){
            const long long r = (long long)tile*128 + w*32 + tt*16 + l15;
            #pragma unroll
            for (int ks = 0; ks < 4; ++ks)
                af[tt][ks] = *(const bf16x8*)(sib + r*DIM + ks*32 + quad*8);
        }
        f32x4 acc[2][8];
        #pragma unroll
        for (int tt = 0; tt < 2; ++tt)
            #pragma unroll
            for (int i = 0; i < 8; ++i) acc[tt][i] = f32x4{0.f,0.f,0.f,0.f};
        #pragma unroll
        for (int ks = 0; ks < 4; ++ks){
            #pragma unroll
            for (int nt = 0; nt < 8; ++nt){
                bf16x8 bfrag = *(const bf16x8*)&lds_w[(nt*16 + l15)*LPAD + ks*32 + quad*8];
                mfma_acc(acc[0][nt], af[0][ks], bfrag);
                mfma_acc(acc[1][nt], af[1][ks], bfrag);
            }
        }
        // sib rows 4q..4q+3: (4q,4q+1)->parent p0, (4q+2,4q+3)->p0+1
        #pragma unroll
        for (int tt = 0; tt < 2; ++tt){
            const long long p0 = (long long)tile*64 + w*16 + tt*8 + quad*2;
            #pragma unroll
            for (int nt = 0; nt < 8; ++nt){
                int col = nt*16 + l15;
                float b = bc[col];
                float r01 = 0.5f*(relu(acc[tt][nt][0]+b) + relu(acc[tt][nt][1]+b));
                float r23 = 0.5f*(relu(acc[tt][nt][2]+b) + relu(acc[tt][nt][3]+b));
                agg[(parent_base + p0    )*DIM + col] = tobf(init[(parent_base + p0    )*DIM + col] + r01);
                agg[(parent_base + p0 + 1)*DIM + col] = tobf(init[(parent_base + p0 + 1)*DIM + col] + r23);
            }
        }
    }
}

// ============================================================================
// down level (tile loop): ctx[child] = (ctxh[parent] + sum_sibs h - h_self)/4
// ============================================================================
__global__ __launch_bounds__(256, 3) void down_kernel(
    const __bf16* __restrict__ wts,     // Wx @32768
    const float* __restrict__ bx,
    const __bf16* __restrict__ agg,
    __bf16* __restrict__ ctx,
    long long parent_base, long long child_base, long long n_par)
{
    __shared__ __bf16 lds_w[128*LPAD];
    __shared__ float lds_ctxh[2][16*132];

    const int t = threadIdx.x;
    const int w = t >> 6, lane = t & 63, quad = lane >> 4, l15 = lane & 15;
    const long long n_child = n_par*8;
    const int ntiles = (int)((n_child + 127) >> 7);
    const int G = gridDim.x;

    load_w_lds(wts + 32768, lds_w, 128);
    __syncthreads();

    int buf = 0;
    for (int tile = blockIdx.x; tile < ntiles; tile += G, buf ^= 1){
        const long long rowbase = (long long)tile*128 + w*32;
        bf16x8 a[2][4];
        #pragma unroll
        for (int tt = 0; tt < 2; ++tt){
            long long r = rowbase + tt*16 + l15;
            if (r >= n_child) r = n_child - 1;
            #pragma unroll
            for (int ks = 0; ks < 4; ++ks)
                a[tt][ks] = *(const bf16x8*)(agg + (child_base + r)*DIM + ks*32 + quad*8);
        }
        if (w == 0){
            bf16x8 pc[4];
            long long p = (long long)tile*16 + l15;
            if (p >= n_par) p = n_par - 1;
            #pragma unroll
            for (int ks = 0; ks < 4; ++ks)
                pc[ks] = *(const bf16x8*)(ctx + (parent_base + p)*DIM + ks*32 + quad*8);
            f32x4 cacc[8];
            #pragma unroll
            for (int i = 0; i < 8; ++i) cacc[i] = f32x4{0.f,0.f,0.f,0.f};
            #pragma unroll
            for (int ks = 0; ks < 4; ++ks){
                #pragma unroll
                for (int nt = 0; nt < 8; ++nt){
                    bf16x8 bfrag = *(const bf16x8*)&lds_w[(nt*16 + l15)*LPAD + ks*32 + quad*8];
                    mfma_acc(cacc[nt], pc[ks], bfrag);
                }
            }
            #pragma unroll
            for (int nt = 0; nt < 8; ++nt){
                int col = nt*16 + l15;
                float b = bx[col];
                #pragma unroll
                for (int rg = 0; rg < 4; ++rg)
                    lds_ctxh[buf][(quad*4 + rg)*132 + col] = relu(cacc[nt][rg] + b);
            }
        }
        f32x4 acc[2][8];
        #pragma unroll
        for (int tt = 0; tt < 2; ++tt)
            #pragma unroll
            for (int i = 0; i < 8; ++i) acc[tt][i] = f32x4{0.f,0.f,0.f,0.f};
        #pragma unroll
        for (int ks = 0; ks < 4; ++ks){
            #pragma unroll
            for (int nt = 0; nt < 8; ++nt){
                bf16x8 bfrag = *(const bf16x8*)&lds_w[(nt*16 + l15)*LPAD + ks*32 + quad*8];
                mfma_acc(acc[0][nt], a[0][ks], bfrag);
                mfma_acc(acc[1][nt], a[1][ks], bfrag);
            }
        }
        __syncthreads();            // ctxh[buf] ready
        #pragma unroll
        for (int tt = 0; tt < 2; ++tt){
            const long long rb = rowbase + tt*16 + quad*4;
            const int p_loc = w*4 + tt*2 + (quad >> 1);
            #pragma unroll
            for (int nt = 0; nt < 8; ++nt){
                int col = nt*16 + l15;
                float b = bx[col];
                float h0 = relu(acc[tt][nt][0]+b), h1 = relu(acc[tt][nt][1]+b);
                float h2 = relu(acc[tt][nt][2]+b), h3 = relu(acc[tt][nt][3]+b);
                float s = h0 + h1 + h2 + h3;
                float ch = lds_ctxh[buf][p_loc*132 + col];
                if (rb   < n_child) ctx[(child_base + rb  )*DIM + col] = tobf((ch + s - h0)*0.25f);
                if (rb+1 < n_child) ctx[(child_base + rb+1)*DIM + col] = tobf((ch + s - h1)*0.25f);
                if (rb+2 < n_child) ctx[(child_base + rb+2)*DIM + col] = tobf((ch + s - h2)*0.25f);
                if (rb+3 < n_child) ctx[(child_base + rb+3)*DIM + col] = tobf((ch + s - h3)*0.25f);
            }
        }
    }
}

// ============================================================================
// final (streaming, barrier-free loop, coalesced out via per-wave LDS)
// ============================================================================
__global__ __launch_bounds__(256, 2) void final_kernel(
    const __bf16* __restrict__ wts,     // Wf @49152, row stride 256
    const __bf16* __restrict__ ctx,
    const __bf16* __restrict__ agg,
    const float* __restrict__ bf_,
    const float* __restrict__ Wh, const float* __restrict__ bh,
    float* __restrict__ out)
{
    __shared__ __bf16 lds_w0[128*LPAD];
    __shared__ __bf16 lds_w1[128*LPAD];
    __shared__ float lds_out[4][32];

    const int t = threadIdx.x;
    const int w = t >> 6, lane = t & 63, quad = lane >> 4, l15 = lane & 15;
    const int ntiles = (int)((NTOT + 127) >> 7);
    const int G = gridDim.x;

    load_w_lds(wts + 49152,       lds_w0, 256);   // Wf[:,0:128]   (ctx half)
    load_w_lds(wts + 49152 + 128, lds_w1, 256);   // Wf[:,128:256] (agg half)
    __syncthreads();

    for (int tile = blockIdx.x; tile < ntiles; tile += G){
        const long long rowbase = (long long)tile*128 + w*32;
        bf16x8 a0[2][4], a1[2][4];
        #pragma unroll
        for (int tt = 0; tt < 2; ++tt){
            long long r = rowbase + tt*16 + l15;
            if (r >= NTOT) r = NTOT - 1;
            #pragma unroll
            for (int ks = 0; ks < 4; ++ks){
                a0[tt][ks] = *(const bf16x8*)(ctx + r*DIM + ks*32 + quad*8);
                a1[tt][ks] = *(const bf16x8*)(agg + r*DIM + ks*32 + quad*8);
            }
        }
        f32x4 acc[2][8];
        #pragma unroll
        for (int tt = 0; tt < 2; ++tt)
            #pragma unroll
            for (int i = 0; i < 8; ++i) acc[tt][i] = f32x4{0.f,0.f,0.f,0.f};
        #pragma unroll
        for (int ks = 0; ks < 4; ++ks){
            #pragma unroll
            for (int nt = 0; nt < 8; ++nt){
                bf16x8 b0 = *(const bf16x8*)&lds_w0[(nt*16 + l15)*LPAD + ks*32 + quad*8];
                bf16x8 b1 = *(const bf16x8*)&lds_w1[(nt*16 + l15)*LPAD + ks*32 + quad*8];
                mfma_acc(acc[0][nt], a0[0][ks], b0);
                mfma_acc(acc[1][nt], a0[1][ks], b0);
                mfma_acc(acc[0][nt], a1[0][ks], b1);
                mfma_acc(acc[1][nt], a1[1][ks], b1);
            }
        }
        #pragma unroll
        for (int tt = 0; tt < 2; ++tt){
            float q0 = 0.f, q1 = 0.f, q2 = 0.f, q3 = 0.f;
            #pragma unroll
            for (int nt = 0; nt < 8; ++nt){
                int col = nt*16 + l15;
                float b = bf_[col], wh = Wh[col];
                q0 += relu(acc[tt][nt][0]+b)*wh;
                q1 += relu(acc[tt][nt][1]+b)*wh;
                q2 += relu(acc[tt][nt][2]+b)*wh;
                q3 += relu(acc[tt][nt][3]+b)*wh;
            }
            #pragma unroll
            for (int m = 1; m < 16; m <<= 1){
                q0 += __shfl_xor(q0, m);
                q1 += __shfl_xor(q1, m);
                q2 += __shfl_xor(q2, m);
                q3 += __shfl_xor(q3, m);
            }
            if (l15 == 0){
                float bb = bh[0];
                int o = tt*16 + quad*4;
                lds_out[w][o  ] = q0 + bb;
                lds_out[w][o+1] = q1 + bb;
                lds_out[w][o+2] = q2 + bb;
                lds_out[w][o+3] = q3 + bb;
            }
        }
        // wave-synchronous transpose -> coalesced 128B store
        long long r = rowbase + lane;
        if (lane < 32 && r < NTOT) out[r] = lds_out[w][lane];
    }
}

// ============================================================================
// tiny up: levels l=2,1,0 in ONE block (cross-level values carried in LDS)
// ============================================================================
__global__ __launch_bounds__(256) void up_tiny_kernel(
    const __bf16* __restrict__ wts,
    const float* __restrict__ init,
    const float* __restrict__ bs, const float* __restrict__ bc,
    __bf16* __restrict__ agg)
{
    __shared__ __bf16 lds_ws[128*LPAD];
    __shared__ __bf16 lds_wc[128*LPAD];
    __shared__ __bf16 lds_sib[32*LPAD];
    __shared__ __bf16 lds_agg[64*LPAD];

    const int t = threadIdx.x;
    const int w = t >> 6, lane = t & 63, quad = lane >> 4, l15 = lane & 15;

    load_w_lds(wts,         lds_ws, 128);
    load_w_lds(wts + 16384, lds_wc, 128);
    __syncthreads();

    const long long CB[3] = {73, 9, 1};
    const long long PB[3] = {9, 1, 0};
    const long long NP[3] = {64, 8, 1};

    for (int li = 0; li < 3; ++li){
        const long long child_base = CB[li], parent_base = PB[li], n_par = NP[li];
        const long long n_child = n_par*8;
        const int ntiles = (int)((n_child + 127) >> 7);
        for (int tile = 0; tile < ntiles; ++tile){
            bf16x8 af[2][4];
            #pragma unroll
            for (int tt = 0; tt < 2; ++tt){
                long long r = (long long)tile*128 + w*32 + tt*16 + l15;
                if (r >= n_child) r = n_child - 1;
                #pragma unroll
                for (int ks = 0; ks < 4; ++ks){
                    if (li == 0)
                        af[tt][ks] = *(const bf16x8*)(agg + (child_base + r)*DIM + ks*32 + quad*8);
                    else
                        af[tt][ks] = *(const bf16x8*)&lds_agg[r*LPAD + ks*32 + quad*8];
                }
            }
            float pinit[2][8];
            const long long p0 = (long long)tile*16 + w*8 + quad*2;
            if (w < 2){
                long long q0 = p0     < n_par ? p0     : n_par - 1;
                long long q1 = p0 + 1 < n_par ? p0 + 1 : n_par - 1;
                #pragma unroll
                for (int nt = 0; nt < 8; ++nt){
                    int col = nt*16 + l15;
                    pinit[0][nt] = init[(parent_base + q0)*DIM + col];
                    pinit[1][nt] = init[(parent_base + q1)*DIM + col];
                }
            }
            f32x4 acc[2][8];
            #pragma unroll
            for (int tt = 0; tt < 2; ++tt)
                #pragma unroll
                for (int i = 0; i < 8; ++i) acc[tt][i] = f32x4{0.f,0.f,0.f,0.f};
            #pragma unroll
            for (int ks = 0; ks < 4; ++ks){
                #pragma unroll
                for (int nt = 0; nt < 8; ++nt){
                    bf16x8 bfrag = *(const bf16x8*)&lds_ws[(nt*16 + l15)*LPAD + ks*32 + quad*8];
                    mfma_acc(acc[0][nt], af[0][ks], bfrag);
                    mfma_acc(acc[1][nt], af[1][ks], bfrag);
                }
            }
            #pragma unroll
            for (int tt = 0; tt < 2; ++tt){
                const int g = w*8 + tt*4 + quad;
                #pragma unroll
                for (int nt = 0; nt < 8; ++nt){
                    int col = nt*16 + l15;
                    float b = bs[col];
                    float s = relu(acc[tt][nt][0]+b) + relu(acc[tt][nt][1]+b)
                            + relu(acc[tt][nt][2]+b) + relu(acc[tt][nt][3]+b);
                    lds_sib[g*LPAD + col] = tobf(s * 0.25f);
                }
            }
            __syncthreads();
            if (w < 2){
                f32x4 a2c[8];
                #pragma unroll
                for (int i = 0; i < 8; ++i) a2c[i] = f32x4{0.f,0.f,0.f,0.f};
                bf16x8 a2[4];
                #pragma unroll
                for (int ks = 0; ks < 4; ++ks)
                    a2[ks] = *(const bf16x8*)&lds_sib[(w*16 + l15)*LPAD + ks*32 + quad*8];
                #pragma unroll
                for (int ks = 0; ks < 4; ++ks){
                    #pragma unroll
                    for (int nt = 0; nt < 8; ++nt){
                        bf16x8 bfrag = *(const bf16x8*)&lds_wc[(nt*16 + l15)*LPAD + ks*32 + quad*8];
                        mfma_acc(a2c[nt], a2[ks], bfrag);
                    }
                }
                #pragma unroll
                for (int nt = 0; nt < 8; ++nt){
                    int col = nt*16 + l15;
                    float b = bc[col];
                    float r01 = 0.5f*(relu(a2c[nt][0]+b) + relu(a2c[nt][1]+b));
                    float r23 = 0.5f*(relu(a2c[nt][2]+b) + relu(a2c[nt][3]+b));
                    if (p0 < n_par){
                        float vv = pinit[0][nt] + r01;
                        agg[(parent_base + p0)*DIM + col] = tobf(vv);
                        lds_agg[p0*LPAD + col] = tobf(vv);
                    }
                    if (p0 + 1 < n_par){
                        float vv = pinit[1][nt] + r23;
                        agg[(parent_base + p0 + 1)*DIM + col] = tobf(vv);
                        lds_agg[(p0 + 1)*LPAD + col] = tobf(vv);
                    }
                }
            }
            __syncthreads();
        }
    }
}

// ============================================================================
// tiny down: levels l=0,1,2 in ONE block; root ctx = ones (constant, not read)
// Also rewrites ctx row 0 = 1.0 for final_kernel.
// ============================================================================
__global__ __launch_bounds__(256) void down_tiny_kernel(
    const __bf16* __restrict__ wts,
    const float* __restrict__ bx,
    const __bf16* __restrict__ agg,
    __bf16* __restrict__ ctx)
{
    __shared__ __bf16 lds_w[128*LPAD];
    __shared__ float lds_ctxh[16*132];
    __shared__ __bf16 lds_ctx[64*LPAD];

    const int t = threadIdx.x;
    const int w = t >> 6, lane = t & 63, quad = lane >> 4, l15 = lane & 15;

    if (t < 128) ctx[t] = tobf(1.0f);      // restore root ctx (sib aliased it)
    load_w_lds(wts + 32768, lds_w, 128);
    __syncthreads();

    const long long PBv[3] = {0, 1, 9};
    const long long CBv[3] = {1, 9, 73};
    const long long NPv[3] = {1, 8, 64};

    for (int li = 0; li < 3; ++li){
        const long long parent_base = PBv[li], child_base = CBv[li], n_par = NPv[li];
        const long long n_child = n_par*8;
        const int ntiles = (int)((n_child + 127) >> 7);
        for (int tile = 0; tile < ntiles; ++tile){
            const long long rowbase = (long long)tile*128 + w*32;
            bf16x8 a[2][4];
            #pragma unroll
            for (int tt = 0; tt < 2; ++tt){
                long long r = rowbase + tt*16 + l15;
                if (r >= n_child) r = n_child - 1;
                #pragma unroll
                for (int ks = 0; ks < 4; ++ks)
                    a[tt][ks] = *(const bf16x8*)(agg + (child_base + r)*DIM + ks*32 + quad*8);
            }
            if (w == 0){
                bf16x8 pc[4];
                if (li == 0){
                    #pragma unroll
                    for (int ks = 0; ks < 4; ++ks)
                        #pragma unroll
                        for (int j = 0; j < 8; ++j) pc[ks][j] = tobf(1.0f);
                } else {
                    long long p = (long long)tile*16 + l15;
                    if (p >= n_par) p = n_par - 1;
                    #pragma unroll
                    for (int ks = 0; ks < 4; ++ks)
                        pc[ks] = *(const bf16x8*)&lds_ctx[p*LPAD + ks*32 + quad*8];
                }
                f32x4 cacc[8];
                #pragma unroll
                for (int i = 0; i < 8; ++i) cacc[i] = f32x4{0.f,0.f,0.f,0.f};
                #pragma unroll
                for (int ks = 0; ks < 4; ++ks){
                    #pragma unroll
                    for (int nt = 0; nt < 8; ++nt){
                        bf16x8 bfrag = *(const bf16x8*)&lds_w[(nt*16 + l15)*LPAD + ks*32 + quad*8];
                        mfma_acc(cacc[nt], pc[ks], bfrag);
                    }
                }
                #pragma unroll
                for (int nt = 0; nt < 8; ++nt){
                    int col = nt*16 + l15;
                    float b = bx[col];
                    #pragma unroll
                    for (int rg = 0; rg < 4; ++rg)
                        lds_ctxh[(quad*4 + rg)*132 + col] = relu(cacc[nt][rg] + b);
                }
            }
            f32x4 acc[2][8];
            #pragma unroll
            for (int tt = 0; tt < 2; ++tt)
                #pragma unroll
                for (int i = 0; i < 8; ++i) acc[tt][i] = f32x4{0.f,0.f,0.f,0.f};
            #pragma unroll
            for (int ks = 0; ks < 4; ++ks){
                #pragma unroll
                for (int nt = 0; nt < 8; ++nt){
                    bf16x8 bfrag = *(const bf16x8*)&lds_w[(nt*16 + l15)*LPAD + ks*32 + quad*8];
                    mfma_acc(acc[0][nt], a[0][ks], bfrag);
                    mfma_acc(acc[1][nt], a[1][ks], bfrag);
                }
            }
            __syncthreads();
            #pragma unroll
            for (int tt = 0; tt < 2; ++tt){
                const long long rb = rowbase + tt*16 + quad*4;
                const int p_loc = w*4 + tt*2 + (quad >> 1);
                #pragma unroll
                for (int nt = 0; nt < 8; ++nt){
                    int col = nt*16 + l15;
                    float b = bx[col];
                    float h0 = relu(acc[tt][nt][0]+b), h1 = relu(acc[tt][nt][1]+b);
                    float h2 = relu(acc[tt][nt][2]+b), h3 = relu(acc[tt][nt][3]+b);
                    float s = h0 + h1 + h2 + h3;
                    float ch = lds_ctxh[p_loc*132 + col];
                    float c0 = (ch + s - h0)*0.25f, c1 = (ch + s - h1)*0.25f;
                    float c2 = (ch + s - h2)*0.25f, c3 = (ch + s - h3)*0.25f;
                    if (rb < n_child){
                        ctx[(child_base + rb)*DIM + col] = tobf(c0);
                        if (li < 2) lds_ctx[rb*LPAD + col] = tobf(c0);
                    }
                    if (rb+1 < n_child){
                        ctx[(child_base + rb+1)*DIM + col] = tobf(c1);
                        if (li < 2) lds_ctx[(rb+1)*LPAD + col] = tobf(c1);
                    }
                    if (rb+2 < n_child){
                        ctx[(child_base + rb+2)*DIM + col] = tobf(c2);
                        if (li < 2) lds_ctx[(rb+2)*LPAD + col] = tobf(c2);
                    }
                    if (rb+3 < n_child){
                        ctx[(child_base + rb+3)*DIM + col] = tobf(c3);
                        if (li < 2) lds_ctx[(rb+3)*LPAD + col] = tobf(c3);
                    }
                }
            }
            __syncthreads();
        }
    }
}

extern "C" void kernel_launch(void* const* d_in, const int* in_sizes, int n_in,
                              void* d_out, int out_size, void* d_ws, size_t ws_size,
                              hipStream_t stream)
{
    const float* init = (const float*)d_in[0];
    const float* Ws  = (const float*)d_in[1];
    const float* bs  = (const float*)d_in[2];
    const float* Wc  = (const float*)d_in[3];
    const float* bc  = (const float*)d_in[4];
    const float* Wx  = (const float*)d_in[5];
    const float* bx  = (const float*)d_in[6];
    const float* Wf  = (const float*)d_in[7];
    const float* bff = (const float*)d_in[8];
    const float* Wh  = (const float*)d_in[9];
    const float* bh  = (const float*)d_in[10];
    float* out = (float*)d_out;

    // ws layout: agg bf16 [N,128] | ctx bf16 [N,128] | weights bf16 (81920)
    // sib scratch aliases the ctx region (dead during the up sweep).
    __bf16* agg = (__bf16*)d_ws;
    __bf16* ctx = agg + NTOT*DIM;
    __bf16* wts = ctx + NTOT*DIM;
    __bf16* sib = ctx;

    static const long long SZ[7] = {1,8,64,512,4096,32768,262144};
    static const long long OF[8] = {0,1,9,73,585,4681,37449,299593};

    prep_kernel<<<dim3(320), dim3(256), 0, stream>>>(Ws, Wc, Wx, Wf, wts);

    // ---- up sweep (streaming split kernels for l5,l4,l3; tiny for l<=2) ----
    up_sib_kernel<true ><<<dim3(1024), dim3(256), 0, stream>>>(
        wts, init, bs, agg, sib, OF[6], SZ[6]);                 // 2048 tiles
    up_par_kernel<<<dim3(512), dim3(256), 0, stream>>>(
        wts, init, bc, sib, agg, OF[5], SZ[5]*2);               // 512 tiles
    up_sib_kernel<false><<<dim3(256), dim3(256), 0, stream>>>(
        wts, init, bs, agg, sib, OF[5], SZ[5]);
    up_par_kernel<<<dim3(64), dim3(256), 0, stream>>>(
        wts, init, bc, sib, agg, OF[4], SZ[4]*2);
    up_sib_kernel<false><<<dim3(32), dim3(256), 0, stream>>>(
        wts, init, bs, agg, sib, OF[4], SZ[4]);
    up_par_kernel<<<dim3(8), dim3(256), 0, stream>>>(
        wts, init, bc, sib, agg, OF[3], SZ[3]*2);
    up_tiny_kernel<<<dim3(1), dim3(256), 0, stream>>>(wts, init, bs, bc, agg);

    // ---- down sweep ----
    down_tiny_kernel<<<dim3(1), dim3(256), 0, stream>>>(wts, bx, agg, ctx);
    down_kernel<<<dim3(32),  dim3(256), 0, stream>>>(wts, bx, agg, ctx, OF[3], OF[4], SZ[3]);
    down_kernel<<<dim3(256), dim3(256), 0, stream>>>(wts, bx, agg, ctx, OF[4], OF[5], SZ[4]);
    down_kernel<<<dim3(768), dim3(256), 0, stream>>>(wts, bx, agg, ctx, OF[5], OF[6], SZ[5]);

    // ---- final (covers node 0 via restored root ctx) ----
    final_kernel<<<dim3(512), dim3(256), 0, stream>>>(wts, ctx, agg, bff, Wh, bh, out);
}

// Round 7
// 506.548 us; speedup vs baseline: 1.2366x; 1.2366x over previous
//
#include <hip/hip_runtime.h>
#include <stdint.h>

#define DIM 128
#define LPAD 136   // padded LDS row stride (bf16): b128 read pattern ~conflict-free

static constexpr long long NTOT = 299593LL;

using bf16x8 = __attribute__((ext_vector_type(8))) __bf16;
using f32x4  = __attribute__((ext_vector_type(4))) float;

__device__ __forceinline__ float relu(float x){ return x > 0.f ? x : 0.f; }
__device__ __forceinline__ __bf16 tobf(float x){ return (__bf16)x; }

__device__ __forceinline__ void mfma_acc(f32x4& acc, bf16x8 a, bf16x8 b){
    acc = __builtin_amdgcn_mfma_f32_16x16x32_bf16(a, b, acc, 0, 0, 0);
}

// cooperative: 128x128 bf16 weight (row stride src_stride) -> padded LDS
template<int NT>
__device__ __forceinline__ void load_w_lds(const __bf16* __restrict__ wsrc,
                                           __bf16* lds, int src_stride){
    int t = threadIdx.x;
    #pragma unroll
    for (int i = 0; i < 2048/NT; ++i){
        int idx = t + i*NT;
        int row = idx >> 4, col8 = (idx & 15) << 3;
        *(uint4*)(&lds[row*LPAD + col8]) = *(const uint4*)(wsrc + row*src_stride + col8);
    }
}
template<int NT>
__device__ __forceinline__ void load_w_regs(const __bf16* __restrict__ wsrc,
                                            uint4* wr, int src_stride){
    int t = threadIdx.x;
    #pragma unroll
    for (int i = 0; i < 2048/NT; ++i){
        int idx = t + i*NT;
        int row = idx >> 4, col8 = (idx & 15) << 3;
        wr[i] = *(const uint4*)(wsrc + row*src_stride + col8);
    }
}
template<int NT>
__device__ __forceinline__ void store_w_regs(const uint4* wr, __bf16* lds){
    int t = threadIdx.x;
    #pragma unroll
    for (int i = 0; i < 2048/NT; ++i){
        int idx = t + i*NT;
        int row = idx >> 4, col8 = (idx & 15) << 3;
        *(uint4*)(&lds[row*LPAD + col8]) = wr[i];
    }
}

// ---- prep: weights fp32->bf16 ----
__global__ __launch_bounds__(256) void prep_kernel(
    const float* __restrict__ Ws, const float* __restrict__ Wc,
    const float* __restrict__ Wx, const float* __restrict__ Wf,
    __bf16* __restrict__ wts)
{
    int idx = blockIdx.x*256 + threadIdx.x;
    if      (idx < 16384) wts[idx] = tobf(Ws[idx]);
    else if (idx < 32768) wts[idx] = tobf(Wc[idx - 16384]);
    else if (idx < 49152) wts[idx] = tobf(Wx[idx - 32768]);
    else if (idx < 81920) wts[idx] = tobf(Wf[idx - 49152]);
}

// ============================================================================
// up level (512 thr, one-shot block = 256 children -> 32 parents):
// agg[l] = init[l] + mean_t relu(Wc . mean_s relu(Ws.child + bs) + bc)
// n_child divisible by 256 (levels 5,4,3). 2 barriers/block.
// ============================================================================
template<bool LEAF>
__global__ __launch_bounds__(512, 4) void up_kernel(
    const __bf16* __restrict__ wts,     // Ws @0, Wc @16384
    const float* __restrict__ init,
    const float* __restrict__ bs, const float* __restrict__ bc,
    __bf16* __restrict__ agg,
    long long child_base, long long parent_base, long long n_par)
{
    __shared__ __bf16 lds_w[128*LPAD];
    __shared__ __bf16 lds_sib[64*LPAD];

    const int t = threadIdx.x;
    const int w = t >> 6, lane = t & 63, quad = lane >> 4, l15 = lane & 15;
    const long long blk = blockIdx.x;
    const long long rowbase = blk*256 + w*32;

    // --- child fragment loads (LEAF: fp32 init, convert, materialize agg) ---
    bf16x8 af[2][4];
    #pragma unroll
    for (int tt = 0; tt < 2; ++tt){
        const long long base = (child_base + rowbase + tt*16 + l15)*DIM;
        #pragma unroll
        for (int ks = 0; ks < 4; ++ks){
            if (LEAF){
                const float* p = init + base + ks*32 + quad*8;
                float4 v0 = *(const float4*)p;
                float4 v1 = *(const float4*)(p + 4);
                bf16x8 a;
                a[0]=tobf(v0.x); a[1]=tobf(v0.y); a[2]=tobf(v0.z); a[3]=tobf(v0.w);
                a[4]=tobf(v1.x); a[5]=tobf(v1.y); a[6]=tobf(v1.z); a[7]=tobf(v1.w);
                af[tt][ks] = a;
                *(uint4*)(agg + base + ks*32 + quad*8) = *(uint4*)&a;   // leaf agg
            } else {
                af[tt][ks] = *(const bf16x8*)(agg + base + ks*32 + quad*8);
            }
        }
    }
    // --- prefetch Wc (regs) and parent init (waves 0-3) ---
    uint4 wcr[4];
    load_w_regs<512>(wts + 16384, wcr, 128);
    float pinit[2][8];
    const long long p0 = blk*32 + w*8 + quad*2;
    if (w < 4){
        #pragma unroll
        for (int nt = 0; nt < 8; ++nt){
            int col = nt*16 + l15;
            pinit[0][nt] = init[(parent_base + p0    )*DIM + col];
            pinit[1][nt] = init[(parent_base + p0 + 1)*DIM + col];
        }
    }
    load_w_lds<512>(wts, lds_w, 128);           // Ws -> LDS
    __syncthreads();

    // --- stage 1: h = relu(Ws.child + bs), sibling mean -> lds_sib ---
    f32x4 acc[2][8];
    #pragma unroll
    for (int tt = 0; tt < 2; ++tt)
        #pragma unroll
        for (int i = 0; i < 8; ++i) acc[tt][i] = f32x4{0.f,0.f,0.f,0.f};
    #pragma unroll
    for (int ks = 0; ks < 4; ++ks){
        #pragma unroll
        for (int nt = 0; nt < 8; ++nt){
            bf16x8 bfrag = *(const bf16x8*)&lds_w[(nt*16 + l15)*LPAD + ks*32 + quad*8];
            mfma_acc(acc[0][nt], af[0][ks], bfrag);
            mfma_acc(acc[1][nt], af[1][ks], bfrag);
        }
    }
    #pragma unroll
    for (int tt = 0; tt < 2; ++tt){
        const int g = w*8 + tt*4 + quad;        // sib row (local, 0..63)
        #pragma unroll
        for (int nt = 0; nt < 8; ++nt){
            int col = nt*16 + l15;
            float b = bs[col];
            float s = relu(acc[tt][nt][0]+b) + relu(acc[tt][nt][1]+b)
                    + relu(acc[tt][nt][2]+b) + relu(acc[tt][nt][3]+b);
            lds_sib[g*LPAD + col] = tobf(s * 0.25f);
        }
    }
    __syncthreads();
    store_w_regs<512>(wcr, lds_w);              // Wc -> LDS (from regs)
    __syncthreads();

    // --- stage 2 (waves 0-3): parent agg ---
    if (w < 4){
        f32x4 a2c[8];
        #pragma unroll
        for (int i = 0; i < 8; ++i) a2c[i] = f32x4{0.f,0.f,0.f,0.f};
        bf16x8 a2[4];
        #pragma unroll
        for (int ks = 0; ks < 4; ++ks)
            a2[ks] = *(const bf16x8*)&lds_sib[(w*16 + l15)*LPAD + ks*32 + quad*8];
        #pragma unroll
        for (int ks = 0; ks < 4; ++ks){
            #pragma unroll
            for (int nt = 0; nt < 8; ++nt){
                bf16x8 bfrag = *(const bf16x8*)&lds_w[(nt*16 + l15)*LPAD + ks*32 + quad*8];
                mfma_acc(a2c[nt], a2[ks], bfrag);
            }
        }
        #pragma unroll
        for (int nt = 0; nt < 8; ++nt){
            int col = nt*16 + l15;
            float b = bc[col];
            float r01 = 0.5f*(relu(a2c[nt][0]+b) + relu(a2c[nt][1]+b));
            float r23 = 0.5f*(relu(a2c[nt][2]+b) + relu(a2c[nt][3]+b));
            agg[(parent_base + p0    )*DIM + col] = tobf(pinit[0][nt] + r01);
            agg[(parent_base + p0 + 1)*DIM + col] = tobf(pinit[1][nt] + r23);
        }
    }
}

// ============================================================================
// down level (512 thr, one-shot block = 32 parents -> 256 children):
// ctx[child] = (ctxh[parent] + sum_sibs h - h_self)/4 . 1 barrier/block.
// ============================================================================
__global__ __launch_bounds__(512, 4) void down_kernel(
    const __bf16* __restrict__ wts,     // Wx @32768
    const float* __restrict__ bx,
    const __bf16* __restrict__ agg,
    __bf16* __restrict__ ctx,
    long long parent_base, long long child_base, long long n_par)
{
    __shared__ __bf16 lds_w[128*LPAD];
    __shared__ float lds_ctxh[32*132];

    const int t = threadIdx.x;
    const int w = t >> 6, lane = t & 63, quad = lane >> 4, l15 = lane & 15;
    const long long blk = blockIdx.x;
    const long long rowbase = blk*256 + w*32;

    // child agg frags (all waves), parent ctx frags (waves 0-1)
    bf16x8 a[2][4];
    #pragma unroll
    for (int tt = 0; tt < 2; ++tt){
        const long long base = (child_base + rowbase + tt*16 + l15)*DIM;
        #pragma unroll
        for (int ks = 0; ks < 4; ++ks)
            a[tt][ks] = *(const bf16x8*)(agg + base + ks*32 + quad*8);
    }
    bf16x8 pc[4];
    if (w < 2){
        const long long p = blk*32 + w*16 + l15;
        #pragma unroll
        for (int ks = 0; ks < 4; ++ks)
            pc[ks] = *(const bf16x8*)(ctx + (parent_base + p)*DIM + ks*32 + quad*8);
    }
    load_w_lds<512>(wts + 32768, lds_w, 128);   // Wx
    __syncthreads();

    // waves 0-1: ctxh for the block's 32 parents
    if (w < 2){
        f32x4 cacc[8];
        #pragma unroll
        for (int i = 0; i < 8; ++i) cacc[i] = f32x4{0.f,0.f,0.f,0.f};
        #pragma unroll
        for (int ks = 0; ks < 4; ++ks){
            #pragma unroll
            for (int nt = 0; nt < 8; ++nt){
                bf16x8 bfrag = *(const bf16x8*)&lds_w[(nt*16 + l15)*LPAD + ks*32 + quad*8];
                mfma_acc(cacc[nt], pc[ks], bfrag);
            }
        }
        #pragma unroll
        for (int nt = 0; nt < 8; ++nt){
            int col = nt*16 + l15;
            float b = bx[col];
            #pragma unroll
            for (int rg = 0; rg < 4; ++rg)
                lds_ctxh[(w*16 + quad*4 + rg)*132 + col] = relu(cacc[nt][rg] + b);
        }
    }
    // all waves: h = relu(Wx.child_agg + bx)
    f32x4 acc[2][8];
    #pragma unroll
    for (int tt = 0; tt < 2; ++tt)
        #pragma unroll
        for (int i = 0; i < 8; ++i) acc[tt][i] = f32x4{0.f,0.f,0.f,0.f};
    #pragma unroll
    for (int ks = 0; ks < 4; ++ks){
        #pragma unroll
        for (int nt = 0; nt < 8; ++nt){
            bf16x8 bfrag = *(const bf16x8*)&lds_w[(nt*16 + l15)*LPAD + ks*32 + quad*8];
            mfma_acc(acc[0][nt], a[0][ks], bfrag);
            mfma_acc(acc[1][nt], a[1][ks], bfrag);
        }
    }
    __syncthreads();            // ctxh ready
    #pragma unroll
    for (int tt = 0; tt < 2; ++tt){
        const long long rb = rowbase + tt*16 + quad*4;
        const int p_loc = w*4 + tt*2 + (quad >> 1);    // local parent (0..31)
        #pragma unroll
        for (int nt = 0; nt < 8; ++nt){
            int col = nt*16 + l15;
            float b = bx[col];
            float h0 = relu(acc[tt][nt][0]+b), h1 = relu(acc[tt][nt][1]+b);
            float h2 = relu(acc[tt][nt][2]+b), h3 = relu(acc[tt][nt][3]+b);
            float s = h0 + h1 + h2 + h3;
            float ch = lds_ctxh[p_loc*132 + col];
            ctx[(child_base + rb  )*DIM + col] = tobf((ch + s - h0)*0.25f);
            ctx[(child_base + rb+1)*DIM + col] = tobf((ch + s - h1)*0.25f);
            ctx[(child_base + rb+2)*DIM + col] = tobf((ch + s - h2)*0.25f);
            ctx[(child_base + rb+3)*DIM + col] = tobf((ch + s - h3)*0.25f);
        }
    }
}

// ============================================================================
// final (512 thr, one-shot block = 256 rows):
// out = relu([ctx,agg] @ Wf^T + bf) @ Wh^T + bh
// ============================================================================
__global__ __launch_bounds__(512, 4) void final_kernel(
    const __bf16* __restrict__ wts,     // Wf @49152, row stride 256
    const __bf16* __restrict__ ctx,
    const __bf16* __restrict__ agg,
    const float* __restrict__ bf_,
    const float* __restrict__ Wh, const float* __restrict__ bh,
    float* __restrict__ out)
{
    __shared__ __bf16 lds_w[128*LPAD];

    const int t = threadIdx.x;
    const int w = t >> 6, lane = t & 63, quad = lane >> 4, l15 = lane & 15;
    const long long rowbase = (long long)blockIdx.x*256 + w*32;

    f32x4 acc[2][8];
    #pragma unroll
    for (int tt = 0; tt < 2; ++tt)
        #pragma unroll
        for (int i = 0; i < 8; ++i) acc[tt][i] = f32x4{0.f,0.f,0.f,0.f};

    #pragma unroll
    for (int half = 0; half < 2; ++half){
        load_w_lds<512>(wts + 49152 + half*128, lds_w, 256);
        __syncthreads();
        const __bf16* src = half ? agg : ctx;
        bf16x8 a[2][4];
        #pragma unroll
        for (int tt = 0; tt < 2; ++tt){
            long long r = rowbase + tt*16 + l15;
            if (r >= NTOT) r = NTOT - 1;
            #pragma unroll
            for (int ks = 0; ks < 4; ++ks)
                a[tt][ks] = *(const bf16x8*)(src + r*DIM + ks*32 + quad*8);
        }
        #pragma unroll
        for (int ks = 0; ks < 4; ++ks){
            #pragma unroll
            for (int nt = 0; nt < 8; ++nt){
                bf16x8 bfrag = *(const bf16x8*)&lds_w[(nt*16 + l15)*LPAD + ks*32 + quad*8];
                mfma_acc(acc[0][nt], a[0][ks], bfrag);
                mfma_acc(acc[1][nt], a[1][ks], bfrag);
            }
        }
        __syncthreads();
    }

    #pragma unroll
    for (int tt = 0; tt < 2; ++tt){
        float q0 = 0.f, q1 = 0.f, q2 = 0.f, q3 = 0.f;
        #pragma unroll
        for (int nt = 0; nt < 8; ++nt){
            int col = nt*16 + l15;
            float b = bf_[col], wh = Wh[col];
            q0 += relu(acc[tt][nt][0]+b)*wh;
            q1 += relu(acc[tt][nt][1]+b)*wh;
            q2 += relu(acc[tt][nt][2]+b)*wh;
            q3 += relu(acc[tt][nt][3]+b)*wh;
        }
        #pragma unroll
        for (int m = 1; m < 16; m <<= 1){
            q0 += __shfl_xor(q0, m);
            q1 += __shfl_xor(q1, m);
            q2 += __shfl_xor(q2, m);
            q3 += __shfl_xor(q3, m);
        }
        if (l15 == 0){
            float bb = bh[0];
            long long r = rowbase + tt*16 + quad*4;
            if (r   < NTOT) out[r  ] = q0 + bb;
            if (r+1 < NTOT) out[r+1] = q1 + bb;
            if (r+2 < NTOT) out[r+2] = q2 + bb;
            if (r+3 < NTOT) out[r+3] = q3 + bb;
        }
    }
}

// ============================================================================
// tiny up: levels l=2,1,0 in ONE 256-thr block (values carried in LDS)
// ============================================================================
__global__ __launch_bounds__(256) void up_tiny_kernel(
    const __bf16* __restrict__ wts,
    const float* __restrict__ init,
    const float* __restrict__ bs, const float* __restrict__ bc,
    __bf16* __restrict__ agg)
{
    __shared__ __bf16 lds_ws[128*LPAD];
    __shared__ __bf16 lds_wc[128*LPAD];
    __shared__ __bf16 lds_sib[32*LPAD];
    __shared__ __bf16 lds_agg[64*LPAD];

    const int t = threadIdx.x;
    const int w = t >> 6, lane = t & 63, quad = lane >> 4, l15 = lane & 15;

    load_w_lds<256>(wts,         lds_ws, 128);
    load_w_lds<256>(wts + 16384, lds_wc, 128);
    __syncthreads();

    const long long CB[3] = {73, 9, 1};
    const long long PB[3] = {9, 1, 0};
    const long long NP[3] = {64, 8, 1};

    for (int li = 0; li < 3; ++li){
        const long long child_base = CB[li], parent_base = PB[li], n_par = NP[li];
        const long long n_child = n_par*8;
        const int ntiles = (int)((n_child + 127) >> 7);
        for (int tile = 0; tile < ntiles; ++tile){
            bf16x8 af[2][4];
            #pragma unroll
            for (int tt = 0; tt < 2; ++tt){
                long long r = (long long)tile*128 + w*32 + tt*16 + l15;
                if (r >= n_child) r = n_child - 1;
                #pragma unroll
                for (int ks = 0; ks < 4; ++ks){
                    if (li == 0)
                        af[tt][ks] = *(const bf16x8*)(agg + (child_base + r)*DIM + ks*32 + quad*8);
                    else
                        af[tt][ks] = *(const bf16x8*)&lds_agg[r*LPAD + ks*32 + quad*8];
                }
            }
            float pinit[2][8];
            const long long p0 = (long long)tile*16 + w*8 + quad*2;
            if (w < 2){
                long long q0 = p0     < n_par ? p0     : n_par - 1;
                long long q1 = p0 + 1 < n_par ? p0 + 1 : n_par - 1;
                #pragma unroll
                for (int nt = 0; nt < 8; ++nt){
                    int col = nt*16 + l15;
                    pinit[0][nt] = init[(parent_base + q0)*DIM + col];
                    pinit[1][nt] = init[(parent_base + q1)*DIM + col];
                }
            }
            f32x4 acc[2][8];
            #pragma unroll
            for (int tt = 0; tt < 2; ++tt)
                #pragma unroll
                for (int i = 0; i < 8; ++i) acc[tt][i] = f32x4{0.f,0.f,0.f,0.f};
            #pragma unroll
            for (int ks = 0; ks < 4; ++ks){
                #pragma unroll
                for (int nt = 0; nt < 8; ++nt){
                    bf16x8 bfrag = *(const bf16x8*)&lds_ws[(nt*16 + l15)*LPAD + ks*32 + quad*8];
                    mfma_acc(acc[0][nt], af[0][ks], bfrag);
                    mfma_acc(acc[1][nt], af[1][ks], bfrag);
                }
            }
            #pragma unroll
            for (int tt = 0; tt < 2; ++tt){
                const int g = w*8 + tt*4 + quad;
                #pragma unroll
                for (int nt = 0; nt < 8; ++nt){
                    int col = nt*16 + l15;
                    float b = bs[col];
                    float s = relu(acc[tt][nt][0]+b) + relu(acc[tt][nt][1]+b)
                            + relu(acc[tt][nt][2]+b) + relu(acc[tt][nt][3]+b);
                    lds_sib[g*LPAD + col] = tobf(s * 0.25f);
                }
            }
            __syncthreads();
            if (w < 2){
                f32x4 a2c[8];
                #pragma unroll
                for (int i = 0; i < 8; ++i) a2c[i] = f32x4{0.f,0.f,0.f,0.f};
                bf16x8 a2[4];
                #pragma unroll
                for (int ks = 0; ks < 4; ++ks)
                    a2[ks] = *(const bf16x8*)&lds_sib[(w*16 + l15)*LPAD + ks*32 + quad*8];
                #pragma unroll
                for (int ks = 0; ks < 4; ++ks){
                    #pragma unroll
                    for (int nt = 0; nt < 8; ++nt){
                        bf16x8 bfrag = *(const bf16x8*)&lds_wc[(nt*16 + l15)*LPAD + ks*32 + quad*8];
                        mfma_acc(a2c[nt], a2[ks], bfrag);
                    }
                }
                #pragma unroll
                for (int nt = 0; nt < 8; ++nt){
                    int col = nt*16 + l15;
                    float b = bc[col];
                    float r01 = 0.5f*(relu(a2c[nt][0]+b) + relu(a2c[nt][1]+b));
                    float r23 = 0.5f*(relu(a2c[nt][2]+b) + relu(a2c[nt][3]+b));
                    if (p0 < n_par){
                        float vv = pinit[0][nt] + r01;
                        agg[(parent_base + p0)*DIM + col] = tobf(vv);
                        lds_agg[p0*LPAD + col] = tobf(vv);
                    }
                    if (p0 + 1 < n_par){
                        float vv = pinit[1][nt] + r23;
                        agg[(parent_base + p0 + 1)*DIM + col] = tobf(vv);
                        lds_agg[(p0 + 1)*LPAD + col] = tobf(vv);
                    }
                }
            }
            __syncthreads();
        }
    }
}

// ============================================================================
// tiny down: levels l=0,1,2 in ONE 256-thr block; root ctx = ones (constant)
// Also writes ctx row 0 = 1.0 for final_kernel.
// ============================================================================
__global__ __launch_bounds__(256) void down_tiny_kernel(
    const __bf16* __restrict__ wts,
    const float* __restrict__ bx,
    const __bf16* __restrict__ agg,
    __bf16* __restrict__ ctx)
{
    __shared__ __bf16 lds_w[128*LPAD];
    __shared__ float lds_ctxh[16*132];
    __shared__ __bf16 lds_ctx[64*LPAD];

    const int t = threadIdx.x;
    const int w = t >> 6, lane = t & 63, quad = lane >> 4, l15 = lane & 15;

    if (t < 128) ctx[t] = tobf(1.0f);      // root ctx row for final
    load_w_lds<256>(wts + 32768, lds_w, 128);
    __syncthreads();

    const long long PBv[3] = {0, 1, 9};
    const long long CBv[3] = {1, 9, 73};
    const long long NPv[3] = {1, 8, 64};

    for (int li = 0; li < 3; ++li){
        const long long parent_base = PBv[li], child_base = CBv[li], n_par = NPv[li];
        const long long n_child = n_par*8;
        const int ntiles = (int)((n_child + 127) >> 7);
        for (int tile = 0; tile < ntiles; ++tile){
            const long long rowbase = (long long)tile*128 + w*32;
            bf16x8 a[2][4];
            #pragma unroll
            for (int tt = 0; tt < 2; ++tt){
                long long r = rowbase + tt*16 + l15;
                if (r >= n_child) r = n_child - 1;
                #pragma unroll
                for (int ks = 0; ks < 4; ++ks)
                    a[tt][ks] = *(const bf16x8*)(agg + (child_base + r)*DIM + ks*32 + quad*8);
            }
            if (w == 0){
                bf16x8 pc[4];
                if (li == 0){
                    #pragma unroll
                    for (int ks = 0; ks < 4; ++ks)
                        #pragma unroll
                        for (int j = 0; j < 8; ++j) pc[ks][j] = tobf(1.0f);
                } else {
                    long long p = (long long)tile*16 + l15;
                    if (p >= n_par) p = n_par - 1;
                    #pragma unroll
                    for (int ks = 0; ks < 4; ++ks)
                        pc[ks] = *(const bf16x8*)&lds_ctx[p*LPAD + ks*32 + quad*8];
                }
                f32x4 cacc[8];
                #pragma unroll
                for (int i = 0; i < 8; ++i) cacc[i] = f32x4{0.f,0.f,0.f,0.f};
                #pragma unroll
                for (int ks = 0; ks < 4; ++ks){
                    #pragma unroll
                    for (int nt = 0; nt < 8; ++nt){
                        bf16x8 bfrag = *(const bf16x8*)&lds_w[(nt*16 + l15)*LPAD + ks*32 + quad*8];
                        mfma_acc(cacc[nt], pc[ks], bfrag);
                    }
                }
                #pragma unroll
                for (int nt = 0; nt < 8; ++nt){
                    int col = nt*16 + l15;
                    float b = bx[col];
                    #pragma unroll
                    for (int rg = 0; rg < 4; ++rg)
                        lds_ctxh[(quad*4 + rg)*132 + col] = relu(cacc[nt][rg] + b);
                }
            }
            f32x4 acc[2][8];
            #pragma unroll
            for (int tt = 0; tt < 2; ++tt)
                #pragma unroll
                for (int i = 0; i < 8; ++i) acc[tt][i] = f32x4{0.f,0.f,0.f,0.f};
            #pragma unroll
            for (int ks = 0; ks < 4; ++ks){
                #pragma unroll
                for (int nt = 0; nt < 8; ++nt){
                    bf16x8 bfrag = *(const bf16x8*)&lds_w[(nt*16 + l15)*LPAD + ks*32 + quad*8];
                    mfma_acc(acc[0][nt], a[0][ks], bfrag);
                    mfma_acc(acc[1][nt], a[1][ks], bfrag);
                }
            }
            __syncthreads();
            #pragma unroll
            for (int tt = 0; tt < 2; ++tt){
                const long long rb = rowbase + tt*16 + quad*4;
                const int p_loc = w*4 + tt*2 + (quad >> 1);
                #pragma unroll
                for (int nt = 0; nt < 8; ++nt){
                    int col = nt*16 + l15;
                    float b = bx[col];
                    float h0 = relu(acc[tt][nt][0]+b), h1 = relu(acc[tt][nt][1]+b);
                    float h2 = relu(acc[tt][nt][2]+b), h3 = relu(acc[tt][nt][3]+b);
                    float s = h0 + h1 + h2 + h3;
                    float ch = lds_ctxh[p_loc*132 + col];
                    float c0 = (ch + s - h0)*0.25f, c1 = (ch + s - h1)*0.25f;
                    float c2 = (ch + s - h2)*0.25f, c3 = (ch + s - h3)*0.25f;
                    if (rb < n_child){
                        ctx[(child_base + rb)*DIM + col] = tobf(c0);
                        if (li < 2) lds_ctx[rb*LPAD + col] = tobf(c0);
                    }
                    if (rb+1 < n_child){
                        ctx[(child_base + rb+1)*DIM + col] = tobf(c1);
                        if (li < 2) lds_ctx[(rb+1)*LPAD + col] = tobf(c1);
                    }
                    if (rb+2 < n_child){
                        ctx[(child_base + rb+2)*DIM + col] = tobf(c2);
                        if (li < 2) lds_ctx[(rb+2)*LPAD + col] = tobf(c2);
                    }
                    if (rb+3 < n_child){
                        ctx[(child_base + rb+3)*DIM + col] = tobf(c3);
                        if (li < 2) lds_ctx[(rb+3)*LPAD + col] = tobf(c3);
                    }
                }
            }
            __syncthreads();
        }
    }
}

extern "C" void kernel_launch(void* const* d_in, const int* in_sizes, int n_in,
                              void* d_out, int out_size, void* d_ws, size_t ws_size,
                              hipStream_t stream)
{
    const float* init = (const float*)d_in[0];
    const float* Ws  = (const float*)d_in[1];
    const float* bs  = (const float*)d_in[2];
    const float* Wc  = (const float*)d_in[3];
    const float* bc  = (const float*)d_in[4];
    const float* Wx  = (const float*)d_in[5];
    const float* bx  = (const float*)d_in[6];
    const float* Wf  = (const float*)d_in[7];
    const float* bff = (const float*)d_in[8];
    const float* Wh  = (const float*)d_in[9];
    const float* bh  = (const float*)d_in[10];
    float* out = (float*)d_out;

    // ws layout: agg bf16 [N,128] | ctx bf16 [N,128] | weights bf16 (81920)
    __bf16* agg = (__bf16*)d_ws;
    __bf16* ctx = agg + NTOT*DIM;
    __bf16* wts = ctx + NTOT*DIM;

    static const long long SZ[7] = {1,8,64,512,4096,32768,262144};
    static const long long OF[8] = {0,1,9,73,585,4681,37449,299593};

    prep_kernel<<<dim3(320), dim3(256), 0, stream>>>(Ws, Wc, Wx, Wf, wts);

    // ---- up sweep ----
    up_kernel<true ><<<dim3(1024), dim3(512), 0, stream>>>(
        wts, init, bs, bc, agg, OF[6], OF[5], SZ[5]);
    up_kernel<false><<<dim3(128), dim3(512), 0, stream>>>(
        wts, init, bs, bc, agg, OF[5], OF[4], SZ[4]);
    up_kernel<false><<<dim3(16), dim3(512), 0, stream>>>(
        wts, init, bs, bc, agg, OF[4], OF[3], SZ[3]);
    up_tiny_kernel<<<dim3(1), dim3(256), 0, stream>>>(wts, init, bs, bc, agg);

    // ---- down sweep ----
    down_tiny_kernel<<<dim3(1), dim3(256), 0, stream>>>(wts, bx, agg, ctx);
    down_kernel<<<dim3(16),  dim3(512), 0, stream>>>(wts, bx, agg, ctx, OF[3], OF[4], SZ[3]);
    down_kernel<<<dim3(128), dim3(512), 0, stream>>>(wts, bx, agg, ctx, OF[4], OF[5], SZ[4]);
    down_kernel<<<dim3(1024),dim3(512), 0, stream>>>(wts, bx, agg, ctx, OF[5], OF[6], SZ[5]);

    // ---- final ----
    final_kernel<<<dim3(1171), dim3(512), 0, stream>>>(wts, ctx, agg, bff, Wh, bh, out);
}